// Round 9
// baseline (169.315 us; speedup 1.0000x reference)
//
#include <hip/hip_runtime.h>
#include <hip/hip_bf16.h>

// Problem dims
#define BS   4096
#define DIN  784
#define DH   400
#define DZ   20

#define KP1  832    // W1b row length (784 -> 832)
#define KPH  416    // h1b / W2c row length (400 -> 416)
#define KPD  448    // h3b / Wcat row length (400 -> 448)

// Output layout (f32 elements)
#define OFF_RMU  0
#define OFF_RVAR 3211264
#define OFF_MU   6422528
#define OFF_LV   6504448
#define OFF_Z    6586368

// Workspace layout (bytes)
#define WS_WCAT  0          // bf16 [1568][448]
#define WS_W2C   1404928    // bf16 [48][416]
#define WS_W1B   1444864    // bf16 [400][832]
#define WS_H1B   2110464    // bf16 [4096][416]
#define WS_H3B   5518336    // bf16 [4096][448]
#define WS_SYNC  9188352    // unsigned[4]: bar_cnt, bar_gen, ticket1, ticket3

#define SQRT20F 4.47213595499958f

using short8 = __attribute__((ext_vector_type(8))) short;
using f4     = __attribute__((ext_vector_type(4))) float;
using i4     = __attribute__((ext_vector_type(4))) int;

__device__ __forceinline__ short bf16r(float f) {
    union { float f; unsigned u; } v; v.f = f;
    unsigned r = (v.u + 0x7fffu + ((v.u >> 16) & 1u)) >> 16;
    return (short)r;
}

// pack 8 f32 (raw bits q0=elems0..3, q1=elems4..7) -> 8 bf16 (truncated)
__device__ __forceinline__ i4 pack8(const i4 q0, const i4 q1) {
    i4 d;
    d[0] = (q0[1] & 0xffff0000) | (int)(((unsigned)q0[0]) >> 16);
    d[1] = (q0[3] & 0xffff0000) | (int)(((unsigned)q0[2]) >> 16);
    d[2] = (q1[1] & 0xffff0000) | (int)(((unsigned)q1[0]) >> 16);
    d[3] = (q1[3] & 0xffff0000) | (int)(((unsigned)q1[2]) >> 16);
    return d;
}

__device__ __forceinline__ void glds16(const void* g, void* l) {
    __builtin_amdgcn_global_load_lds(
        (const __attribute__((address_space(1))) unsigned int*)g,
        (__attribute__((address_space(3))) unsigned int*)l,
        16, 0, 0);
}

// Grid barrier: generation counter, device-scope atomics, release/acquire
// fences. All 256 blocks provably co-resident (LDS forces 1 block/CU,
// grid == CU count). sync[0]=count, sync[1]=generation (zeroed per call).
__device__ __forceinline__ void gridbar(unsigned* sync) {
    __syncthreads();
    if (threadIdx.x == 0) {
        __threadfence();                              // release
        unsigned g = atomicAdd(&sync[1], 0u);
        if (atomicAdd(&sync[0], 1u) == 255u) {        // 256th arrival
            atomicExch(&sync[0], 0u);
            __threadfence();                          // cnt reset before gen bump
            atomicAdd(&sync[1], 1u);
        } else {
            while (atomicAdd(&sync[1], 0u) == g) __builtin_amdgcn_s_sleep(2);
        }
        __threadfence();                              // acquire
    }
    __syncthreads();
}

struct P1 { short sA[2][128 * 64]; short sB[2][80 * 64]; };    // 52KB
struct P2 {
    short sA[16 * 416]; short sB[48 * 416]; short sW[400 * 40];
    float muv[2][16][20]; short zl[16 * 40]; short h3s[16 * 448];
};                                                              // ~103.4KB
struct P3 { short sA[2][128 * 64]; short sB[2][112 * 64]; };   // 60KB
union SMem { P1 p1; P2 p2; P3 p3; };

// ---------------------------------------------------------------------------
// fused: 256 blocks x 512 threads, 1 block/CU (LDS-forced), persistent.
// ---------------------------------------------------------------------------
__global__ __launch_bounds__(512, 1)
void fused(const float* __restrict__ x, const float* __restrict__ W1,
           const float* __restrict__ b1,
           const float* __restrict__ W21, const float* __restrict__ b21,
           const float* __restrict__ W22, const float* __restrict__ b22,
           const float* __restrict__ W3, const float* __restrict__ b3,
           const float* __restrict__ W41, const float* __restrict__ b41,
           const float* __restrict__ W42, const float* __restrict__ b42,
           float* __restrict__ out, char* __restrict__ ws) {
    __shared__ SMem sm;
    __shared__ unsigned smt;

    unsigned* sync = (unsigned*)(ws + WS_SYNC);
    const int tid = threadIdx.x;
    const int bid = blockIdx.x;
    const int w = tid >> 6, l = tid & 63, lg = l >> 4, lr = l & 15;

    short* w1b  = (short*)(ws + WS_W1B);
    short* wcat = (short*)(ws + WS_WCAT);
    short* w2c  = (short*)(ws + WS_W2C);
    short* h1b  = (short*)(ws + WS_H1B);
    short* h3b  = (short*)(ws + WS_H3B);

    // ================= phase 0: weight conversion (RTNE) =================
    {
        const int N0 = 400 * 104;             // W1b chunks
        const int N1 = N0 + 1568 * 56;        // Wcat
        const int N2 = N1 + 48 * 52;          // W2c
        for (int p = bid * 512 + tid; p < N2; p += 131072) {
            const float* sr = nullptr;
            short* dst;
            int c, DC;
            if (p < N0) {
                int row = p / 104; c = p - row * 104; DC = 98;
                sr = W1 + (size_t)row * DIN;
                dst = w1b + (size_t)row * KP1 + c * 8;
            } else if (p < N1) {
                int q = p - N0;
                int row = q / 56; c = q - row * 56; DC = 50;
                sr = (row < 784) ? (W41 + (size_t)row * DH)
                                 : (W42 + (size_t)(row - 784) * DH);
                dst = wcat + (size_t)row * KPD + c * 8;
            } else {
                int q = p - N1;
                int row = q / 52; c = q - row * 52; DC = 50;
                if (row < 20)      sr = W21 + (size_t)row * DH;
                else if (row < 40) sr = W22 + (size_t)(row - 20) * DH;
                else               sr = nullptr;
                dst = w2c + (size_t)row * KPH + c * 8;
            }
            short8 v;
            if (c < DC && sr) {
                f4 a = *(const f4*)(sr + c * 8);
                f4 b = *(const f4*)(sr + c * 8 + 4);
#pragma unroll
                for (int e = 0; e < 4; ++e) { v[e] = bf16r(a[e]); v[4 + e] = bf16r(b[e]); }
            } else {
#pragma unroll
                for (int e = 0; e < 8; ++e) v[e] = 0;
            }
            *(short8*)dst = v;
        }
    }
    gridbar(sync);

    // ================= phase 1: gemm1 (160 tiles, BM=128 BN=80 BK=64) ====
    for (;;) {
        if (tid == 0) smt = atomicAdd(&sync[2], 1u);
        __syncthreads();
        const unsigned t = smt;
        __syncthreads();
        if (t >= 160u) break;
        const int swz = (t & 7) * 20 + (t >> 3);    // 160%8==0, bijective
        const int bm = swz / 5, bn = swz - bm * 5;

        f4 acc[5] = {};
        i4 ar[4];

        auto a_load = [&](int kt) {
#pragma unroll
            for (int i = 0; i < 2; ++i) {
                int c = tid + i * 512;              // 1024 chunks
                int row = c >> 3, kc = c & 7;
                int gk = kt * 64 + kc * 8;
                if (gk < DIN) {
                    const i4* p = (const i4*)(x + (size_t)(bm * 128 + row) * DIN + gk);
                    ar[2 * i] = p[0]; ar[2 * i + 1] = p[1];
                } else {
                    ar[2 * i] = (i4){0, 0, 0, 0}; ar[2 * i + 1] = (i4){0, 0, 0, 0};
                }
            }
        };
        auto a_write = [&](int buf) {
#pragma unroll
            for (int i = 0; i < 2; ++i) {
                int c = tid + i * 512;
                int row = c >> 3, kc = c & 7;
                *(i4*)&sm.p1.sA[buf][(row * 8 + (kc ^ (row & 7))) * 8] =
                    pack8(ar[2 * i], ar[2 * i + 1]);
            }
        };
        auto b_stage = [&](int buf, int kt) {       // 640 chunks
#pragma unroll
            for (int it = 0; it < 2; ++it) {
                int p = it * 512 + tid;
                if (p < 640) {
                    int r = p >> 3, kc = (p & 7) ^ (r & 7);
                    glds16(w1b + (size_t)(bn * 80 + r) * KP1 + kt * 64 + kc * 8,
                           &sm.p1.sB[buf][p * 8]);
                }
            }
        };
        auto compute = [&](int buf) {
            const int row = w * 16 + lr;            // 8 waves x 16 rows = 128
#pragma unroll
            for (int kk = 0; kk < 2; ++kk) {
                short8 a = *(const short8*)&sm.p1.sA[buf][(row * 8 + ((kk * 4 + lg) ^ (row & 7))) * 8];
#pragma unroll
                for (int ni = 0; ni < 5; ++ni) {
                    int brw = ni * 16 + lr;
                    short8 b = *(const short8*)&sm.p1.sB[buf][(brw * 8 + ((kk * 4 + lg) ^ (brw & 7))) * 8];
                    acc[ni] = __builtin_amdgcn_mfma_f32_16x16x32_bf16(a, b, acc[ni], 0, 0, 0);
                }
            }
        };

        a_load(0); b_stage(0, 0); a_write(0);
        __syncthreads();
        for (int kt = 0; kt < 13; ++kt) {
            const int cur = kt & 1;
            if (kt < 12) { a_load(kt + 1); b_stage(cur ^ 1, kt + 1); }
            compute(cur);
            if (kt < 12) a_write(cur ^ 1);
            __syncthreads();
        }

#pragma unroll
        for (int ni = 0; ni < 5; ++ni) {
            int col = bn * 80 + ni * 16 + lr;
            float bias = b1[col];
#pragma unroll
            for (int r = 0; r < 4; ++r) {
                int row = bm * 128 + w * 16 + lg * 4 + r;
                float v = acc[ni][r] + bias;
                h1b[(size_t)row * KPH + col] = bf16r(v > 0.f ? v : 0.f);
            }
        }
        if (bn == 4) {   // zero-pad h1b cols 400..415 for this row-group
            for (int p = tid; p < 128 * 16; p += 512) {
                int r = p >> 4, c = 400 + (p & 15);
                h1b[(size_t)(bm * 128 + r) * KPH + c] = 0;
            }
        }
    }
    gridbar(sync);

    // ================= phase 2: mid (tile = bid, 16 rows) =================
    {
        const int r0 = bid * 16;
#pragma unroll
        for (int it = 0; it < 2; ++it) {            // sA: 832 chunks
            int p = it * 512 + tid;
            if (p < 832) {
                int r = p / 52, cp = p - r * 52, c = cp ^ (r & 3);
                glds16(h1b + (size_t)(r0 + r) * KPH + c * 8, &sm.p2.sA[p * 8]);
            }
        }
#pragma unroll
        for (int it = 0; it < 5; ++it) {            // sB: 2496 chunks
            int p = it * 512 + tid;
            if (p < 2496) {
                int r = p / 52, cp = p - r * 52, c = cp ^ (r & 3);
                glds16(w2c + (size_t)r * KPH + c * 8, &sm.p2.sB[p * 8]);
            }
        }
        if (tid < 400) {                            // sW: W3 -> bf16 [400][40]
            int r = tid;
            const float* src = W3 + (size_t)r * DZ;
            f4 f0 = *(const f4*)src;
            f4 f1 = *(const f4*)(src + 4);
            f4 f2 = *(const f4*)(src + 8);
            f4 f3 = *(const f4*)(src + 12);
            f4 f5 = *(const f4*)(src + 16);
            short8 c0, c1, c2, c3;
#pragma unroll
            for (int e = 0; e < 4; ++e) {
                c0[e] = bf16r(f0[e]); c0[4 + e] = bf16r(f1[e]);
                c1[e] = bf16r(f2[e]); c1[4 + e] = bf16r(f3[e]);
                c2[e] = bf16r(f5[e]); c2[4 + e] = 0;
                c3[e] = 0; c3[4 + e] = 0;
            }
            *(short8*)&sm.p2.sW[r * 40 + 0]  = c0;
            *(short8*)&sm.p2.sW[r * 40 + 8]  = c1;
            *(short8*)&sm.p2.sW[r * 40 + 16] = c2;
            *(short8*)&sm.p2.sW[r * 40 + 24] = c3;
        }
        __syncthreads();

        if (w == 0) {                               // mu/lv MFMA (wave 0)
            f4 a3[3] = {};
#pragma unroll
            for (int kk = 0; kk < 13; ++kk) {
                short8 a = *(const short8*)&sm.p2.sA[(lr * 52 + ((kk * 4 + lg) ^ (lr & 3))) * 8];
#pragma unroll
                for (int ni = 0; ni < 3; ++ni) {
                    int br = ni * 16 + lr;
                    short8 b = *(const short8*)&sm.p2.sB[(br * 52 + ((kk * 4 + lg) ^ (br & 3))) * 8];
                    a3[ni] = __builtin_amdgcn_mfma_f32_16x16x32_bf16(a, b, a3[ni], 0, 0, 0);
                }
            }
#pragma unroll
            for (int ni = 0; ni < 3; ++ni) {
                int n = ni * 16 + lr;
                if (n < 40) {
                    float bias = (n < 20) ? b21[n] : b22[n - 20];
#pragma unroll
                    for (int r = 0; r < 4; ++r) {
                        int row = lg * 4 + r;
                        float v = a3[ni][r] + bias;
                        if (n < 20) {
                            sm.p2.muv[0][row][n] = v;
                            out[OFF_MU + (size_t)(r0 + row) * 20 + n] = v;
                        } else {
                            sm.p2.muv[1][row][n - 20] = v;
                            out[OFF_LV + (size_t)(r0 + row) * 20 + (n - 20)] = v;
                        }
                    }
                }
            }
        }
        __syncthreads();

        if (tid < 80) {                             // z_last bf16 [16][40]
            int row = tid / 5, c = tid - (tid / 5) * 5;
            short8 v;
#pragma unroll
            for (int e = 0; e < 8; ++e) {
                int j = c * 8 + e;
                float val = 0.f;
                if (j < 20) {
                    val = sm.p2.muv[0][row][j];
                    if (j == 19) val -= SQRT20F * sm.p2.muv[1][row][19];
                }
                v[e] = bf16r(val);
            }
            *(short8*)&sm.p2.zl[row * 40 + c * 8] = v;
        } else if (tid < 176) {                     // h3s pad cols 400..447
            int q = tid - 80;
            int row = q / 6, c = q - (q / 6) * 6;
            short8 zz;
#pragma unroll
            for (int e = 0; e < 8; ++e) zz[e] = 0;
            *(short8*)&sm.p2.h3s[row * 448 + 400 + c * 8] = zz;
        }
        __syncthreads();

        for (int f = w; f < 25; f += 8) {           // h3 MFMA, 8 waves
            int n0 = f * 16;
            short8 a = *(const short8*)&sm.p2.zl[lr * 40 + lg * 8];
            short8 b = *(const short8*)&sm.p2.sW[(n0 + lr) * 40 + lg * 8];
            f4 z4 = {};
            f4 accv = __builtin_amdgcn_mfma_f32_16x16x32_bf16(a, b, z4, 0, 0, 0);
            int n = n0 + lr;
            float bias = b3[n];
#pragma unroll
            for (int r = 0; r < 4; ++r) {
                int row = lg * 4 + r;
                float v = accv[r] + bias;
                sm.p2.h3s[row * 448 + n] = bf16r(v > 0.f ? v : 0.f);
            }
        }
        __syncthreads();

#pragma unroll
        for (int it = 0; it < 2; ++it) {            // coalesced h3b dump
            int p = it * 512 + tid;
            if (p < 896) {
                int row = p / 56, c = p - (p / 56) * 56;
                *(short8*)(h3b + (size_t)(r0 + row) * KPD + c * 8) =
                    *(const short8*)&sm.p2.h3s[row * 448 + c * 8];
            }
        }
    }
    gridbar(sync);

    // ================= phase 3: 512 tickets = 64 z + 448 gemm4 ===========
    for (;;) {
        if (tid == 0) smt = atomicAdd(&sync[3], 1u);
        __syncthreads();
        const unsigned t = smt;
        __syncthreads();
        if (t >= 512u) break;

        if (t < 64u) {
            // ---- z chunk (13.1MB writes overlap gemm compute) ----
            const int zb = (int)t;
#pragma unroll 5
            for (int it = 0; it < 25; ++it) {
                int idx = it * 32768 + zb * 512 + tid;   // < 819200 f4-chunks
                int s = idx / 20480;
                int rem = idx - s * 20480;
                int b = rem / 5, j4 = rem - b * 5;
                int sp = (s < 20) ? s : s - 20;
                f4 v = *(const f4*)(out + OFF_MU + (size_t)b * 20 + j4 * 4);
                if ((sp >> 2) == j4) {
                    float add = ((s < 20) ? SQRT20F : -SQRT20F) *
                                out[OFF_LV + (size_t)b * 20 + sp];
                    int e = sp & 3;
#pragma unroll
                    for (int k = 0; k < 4; ++k) v[k] += (e == k) ? add : 0.f;
                }
                *(f4*)(out + OFF_Z + (size_t)idx * 4) = v;
            }
            continue;
        }

        // ---- gemm4 tile (BM=128, BN=112, BK=64, 7 steps) ----
        const int g = (int)t - 64;
        const int swz = (g & 7) * 56 + (g >> 3);    // 448%8==0, bijective
        const int bm = swz / 14, bn = swz - bm * 14;

        f4 acc[7] = {};

        auto stage = [&](int buf, int kt) {
#pragma unroll
            for (int i = 0; i < 2; ++i) {           // A: 1024 chunks
                int c = tid + i * 512;
                int r = c >> 3, kc = (c & 7) ^ (r & 7);
                glds16(h3b + (size_t)(bm * 128 + r) * KPD + kt * 64 + kc * 8,
                       &sm.p3.sA[buf][c * 8]);
            }
#pragma unroll
            for (int i = 0; i < 2; ++i) {           // B: 896 chunks
                int c = tid + i * 512;
                if (c < 896) {
                    int r = c >> 3, kc = (c & 7) ^ (r & 7);
                    glds16(wcat + (size_t)(bn * 112 + r) * KPD + kt * 64 + kc * 8,
                           &sm.p3.sB[buf][c * 8]);
                }
            }
        };

        stage(0, 0);
        __syncthreads();
        for (int kt = 0; kt < 7; ++kt) {
            const int cur = kt & 1;
            if (kt < 6) stage(cur ^ 1, kt + 1);
            const int row = w * 16 + lr;            // 8 waves x 16 rows = 128
#pragma unroll
            for (int kk = 0; kk < 2; ++kk) {
                short8 a = *(const short8*)&sm.p3.sA[cur][(row * 8 + ((kk * 4 + lg) ^ (row & 7))) * 8];
#pragma unroll
                for (int ni = 0; ni < 7; ++ni) {
                    int br = ni * 16 + lr;
                    short8 b = *(const short8*)&sm.p3.sB[cur][(br * 8 + ((kk * 4 + lg) ^ (br & 7))) * 8];
                    acc[ni] = __builtin_amdgcn_mfma_f32_16x16x32_bf16(a, b, acc[ni], 0, 0, 0);
                }
            }
            __syncthreads();
        }

        const bool first = (bn < 7);
#pragma unroll
        for (int ni = 0; ni < 7; ++ni) {
            int colt = bn * 112 + ni * 16 + lr;
            int cc = first ? colt : colt - 784;
            float bias = first ? b41[cc] : b42[cc];
            size_t base = first ? (size_t)OFF_RMU : (size_t)OFF_RVAR;
#pragma unroll
            for (int r = 0; r < 4; ++r) {
                size_t row = (size_t)(bm * 128 + w * 16 + lg * 4 + r);
                out[base + row * DIN + cc] = acc[ni][r] + bias;
            }
        }
    }
}

// ---------------------------------------------------------------------------
extern "C" void kernel_launch(void* const* d_in, const int* in_sizes, int n_in,
                              void* d_out, int out_size, void* d_ws, size_t ws_size,
                              hipStream_t stream) {
    const float* x   = (const float*)d_in[0];
    const float* W1  = (const float*)d_in[1];
    const float* b1  = (const float*)d_in[2];
    const float* W21 = (const float*)d_in[3];
    const float* b21 = (const float*)d_in[4];
    const float* W22 = (const float*)d_in[5];
    const float* b22 = (const float*)d_in[6];
    const float* W3  = (const float*)d_in[7];
    const float* b3  = (const float*)d_in[8];
    const float* W41 = (const float*)d_in[9];
    const float* b41 = (const float*)d_in[10];
    const float* W42 = (const float*)d_in[11];
    const float* b42 = (const float*)d_in[12];

    float* out = (float*)d_out;
    char*  ws  = (char*)d_ws;

    // zero barrier count/gen + phase tickets (deterministic per call)
    hipMemsetAsync(ws + WS_SYNC, 0, 64, stream);
    fused<<<256, 512, 0, stream>>>(x, W1, b1, W21, b21, W22, b22,
                                   W3, b3, W41, b41, W42, b42, out, ws);
}

// Round 10
// 45.026 us; speedup vs baseline: 3.7604x; 3.7604x over previous
//
#include <hip/hip_runtime.h>
#include <hip/hip_bf16.h>

// Problem dims
#define BS   4096
#define DIN  784
#define DH   400
#define DZ   20

#define KP1  832    // W1b row length (784 -> 832 = 13*64)
#define KPH  416    // h1b / W2c row length (400 -> 416)
#define KPD  448    // h3b / Wcat row length (400 -> 448)

// Output layout (f32 elements)
#define OFF_RMU  0
#define OFF_RVAR 3211264
#define OFF_MU   6422528
#define OFF_LV   6504448
#define OFF_Z    6586368

// Workspace layout (bytes)
#define WS_WCAT  0          // bf16 [1568][448] = 1404928 (rows 0..783 W41, 784.. W42)
#define WS_W2C   1404928    // bf16 [48][416]   = 39936
#define WS_W1B   1444864    // bf16 [400][832]  = 665600
#define WS_H1B   2110464    // bf16 [4096][416] = 3407872
#define WS_H3B   5518336    // bf16 [4096][448] = 3670016
// total 9188352 bytes

#define SQRT20F 4.47213595499958f

using short8 = __attribute__((ext_vector_type(8))) short;
using f4     = __attribute__((ext_vector_type(4))) float;
using i4     = __attribute__((ext_vector_type(4))) int;

__device__ __forceinline__ short bf16r(float f) {
    union { float f; unsigned u; } v; v.f = f;
    unsigned r = (v.u + 0x7fffu + ((v.u >> 16) & 1u)) >> 16;
    return (short)r;
}

// pack 8 f32 (raw bits q0=elems0..3, q1=elems4..7) -> 8 bf16 (truncated)
__device__ __forceinline__ i4 pack8(const i4 q0, const i4 q1) {
    i4 d;
    d[0] = (q0[1] & 0xffff0000) | (int)(((unsigned)q0[0]) >> 16);
    d[1] = (q0[3] & 0xffff0000) | (int)(((unsigned)q0[2]) >> 16);
    d[2] = (q1[1] & 0xffff0000) | (int)(((unsigned)q1[0]) >> 16);
    d[3] = (q1[3] & 0xffff0000) | (int)(((unsigned)q1[2]) >> 16);
    return d;
}

__device__ __forceinline__ void glds16(const void* g, void* l) {
    __builtin_amdgcn_global_load_lds(
        (const __attribute__((address_space(1))) unsigned int*)g,
        (__attribute__((address_space(3))) unsigned int*)l,
        16, 0, 0);
}

// ---------------------------------------------------------------------------
// k0: one-time weight conversion f32 -> bf16 (RTNE), zero K-padding.
// W1 -> W1b[400][832]; W41/W42 -> Wcat[1568][448]; W21/W22 -> W2c[48][416].
// ---------------------------------------------------------------------------
__global__ void k0(const float* __restrict__ W1, const float* __restrict__ W41,
                   const float* __restrict__ W42, const float* __restrict__ W21,
                   const float* __restrict__ W22, char* __restrict__ ws) {
    const int N0 = 400 * 104;                 // W1b
    const int N1 = N0 + 1568 * 56;            // Wcat
    const int N2 = N1 + 48 * 52;              // W2c
    int gid = blockIdx.x * 256 + threadIdx.x;
    if (gid >= N2) return;

    const float* sr = nullptr;
    short* dst;
    int c, DC;
    if (gid < N0) {
        int row = gid / 104; c = gid - row * 104; DC = 98;
        sr = W1 + (size_t)row * DIN;
        dst = (short*)(ws + WS_W1B) + (size_t)row * KP1 + c * 8;
    } else if (gid < N1) {
        int p = gid - N0;
        int row = p / 56; c = p - row * 56; DC = 50;
        sr = (row < 784) ? (W41 + (size_t)row * DH) : (W42 + (size_t)(row - 784) * DH);
        dst = (short*)(ws + WS_WCAT) + (size_t)row * KPD + c * 8;
    } else {
        int p = gid - N1;
        int row = p / 52; c = p - row * 52; DC = 50;
        if (row < 20)      sr = W21 + (size_t)row * DH;
        else if (row < 40) sr = W22 + (size_t)(row - 20) * DH;
        else               sr = nullptr;
        dst = (short*)(ws + WS_W2C) + (size_t)row * KPH + c * 8;
    }
    short8 v;
    if (c < DC && sr) {
        f4 a = *(const f4*)(sr + c * 8);
        f4 b = *(const f4*)(sr + c * 8 + 4);
#pragma unroll
        for (int e = 0; e < 4; ++e) { v[e] = bf16r(a[e]); v[4 + e] = bf16r(b[e]); }
    } else {
#pragma unroll
        for (int e = 0; e < 8; ++e) v[e] = 0;
    }
    *(short8*)dst = v;
}

// ---------------------------------------------------------------------------
// k1: h1b = bf16(relu(x @ W1^T + b1)). BM=64, BN=80, BK=64, 13 steps, dbuf.
// A (x f32) reg-staged with bit-truncation; B (W1b) via global_load_lds.
// grid 320 (XCD-swizzled), 256 threads.
// ---------------------------------------------------------------------------
__global__ __launch_bounds__(256)
void k1(const float* __restrict__ x, const float* __restrict__ b1,
        const short* __restrict__ W1b, short* __restrict__ h1b) {
    __shared__ short sA[2][64 * 64];   // 8KB each
    __shared__ short sB[2][80 * 64];   // 10KB each

    const int tid = threadIdx.x;
    const int bid = blockIdx.x;
    const int swz = (bid & 7) * 40 + (bid >> 3);
    const int bm = swz / 5, bn = swz - bm * 5;
    const int w = tid >> 6, l = tid & 63, lg = l >> 4, lr = l & 15;

    f4 acc[5] = {};
    i4 ar[4];

    auto a_load = [&](int kt) {
#pragma unroll
        for (int i = 0; i < 2; ++i) {
            int c = tid + i * 256;
            int row = c >> 3, kc = c & 7;
            int gk = kt * 64 + kc * 8;
            if (gk < DIN) {
                const i4* p = (const i4*)(x + (size_t)(bm * 64 + row) * DIN + gk);
                ar[2 * i] = p[0]; ar[2 * i + 1] = p[1];
            } else {
                ar[2 * i] = (i4){0, 0, 0, 0};
                ar[2 * i + 1] = (i4){0, 0, 0, 0};
            }
        }
    };
    auto a_write = [&](int buf) {
#pragma unroll
        for (int i = 0; i < 2; ++i) {
            int c = tid + i * 256;
            int row = c >> 3, kc = c & 7;
            *(i4*)&sA[buf][(row * 8 + (kc ^ (row & 7))) * 8] = pack8(ar[2 * i], ar[2 * i + 1]);
        }
    };
    auto b_stage = [&](int buf, int kt) {
#pragma unroll
        for (int it = 0; it < 3; ++it) {
            int p = it * 256 + tid;
            if (p < 640) {
                int r = p >> 3, kc = (p & 7) ^ (r & 7);
                glds16(W1b + (size_t)(bn * 80 + r) * KP1 + kt * 64 + kc * 8, &sB[buf][p * 8]);
            }
        }
    };
    auto compute = [&](int buf) {
        const int row = w * 16 + lr;
#pragma unroll
        for (int kk = 0; kk < 2; ++kk) {
            short8 a = *(const short8*)&sA[buf][(row * 8 + ((kk * 4 + lg) ^ (row & 7))) * 8];
#pragma unroll
            for (int ni = 0; ni < 5; ++ni) {
                int brw = ni * 16 + lr;
                short8 b = *(const short8*)&sB[buf][(brw * 8 + ((kk * 4 + lg) ^ (brw & 7))) * 8];
                acc[ni] = __builtin_amdgcn_mfma_f32_16x16x32_bf16(a, b, acc[ni], 0, 0, 0);
            }
        }
    };

    a_load(0); b_stage(0, 0); a_write(0);
    __syncthreads();
    for (int kt = 0; kt < 13; ++kt) {
        const int cur = kt & 1;
        if (kt < 12) { a_load(kt + 1); b_stage(cur ^ 1, kt + 1); }
        compute(cur);
        if (kt < 12) a_write(cur ^ 1);
        __syncthreads();
    }

#pragma unroll
    for (int ni = 0; ni < 5; ++ni) {
        int col = bn * 80 + ni * 16 + lr;
        float bias = b1[col];
#pragma unroll
        for (int r = 0; r < 4; ++r) {
            int row = bm * 64 + w * 16 + lg * 4 + r;
            float v = acc[ni][r] + bias;
            h1b[(size_t)row * KPH + col] = bf16r(v > 0.f ? v : 0.f);
        }
    }
    if (bn == 4) {
        for (int p = tid; p < 64 * 16; p += 256) {
            int r = p >> 4, c = 400 + (p & 15);
            h1b[(size_t)(bm * 64 + r) * KPH + c] = 0;
        }
    }
}

// ---------------------------------------------------------------------------
// K2 (mid): per block 16 batch rows: mu/lv MFMA -> out+LDS; z writes; h3 MFMA
// -> h3b (coalesced via LDS). grid 256 x 256.
// ---------------------------------------------------------------------------
__global__ __launch_bounds__(256)
void k_mid(const short* __restrict__ h1b, const short* __restrict__ w2c,
           const float* __restrict__ W3, const float* __restrict__ b3,
           const float* __restrict__ b21, const float* __restrict__ b22,
           float* __restrict__ out, short* __restrict__ h3b) {
    __shared__ short sA[16 * 416];
    __shared__ short sB[48 * 416];
    __shared__ short sW[400 * 40];
    __shared__ float muv[2][16][20];
    __shared__ short zl[16 * 40];
    __shared__ short h3s[16 * 448];

    const int tid = threadIdx.x;
    const int blk = blockIdx.x;
    const int w = tid >> 6, l = tid & 63, lg = l >> 4, lr = l & 15;
    const int r0 = blk * 16;

#pragma unroll
    for (int it = 0; it < 4; ++it) {
        int p = it * 256 + tid;
        if (p < 832) {
            int r = p / 52, cp = p - r * 52, c = cp ^ (r & 3);
            glds16(h1b + (size_t)(r0 + r) * KPH + c * 8, &sA[p * 8]);
        }
    }
#pragma unroll
    for (int it = 0; it < 10; ++it) {
        int p = it * 256 + tid;
        if (p < 2496) {
            int r = p / 52, cp = p - r * 52, c = cp ^ (r & 3);
            glds16(w2c + (size_t)r * KPH + c * 8, &sB[p * 8]);
        }
    }
    if (tid < 200) {
#pragma unroll
        for (int i = 0; i < 2; ++i) {
            int r = tid + i * 200;
            const float* src = W3 + (size_t)r * DZ;
            f4 f0 = *(const f4*)src;
            f4 f1 = *(const f4*)(src + 4);
            f4 f2 = *(const f4*)(src + 8);
            f4 f3 = *(const f4*)(src + 12);
            f4 f5 = *(const f4*)(src + 16);
            short8 c0, c1, c2, c3;
#pragma unroll
            for (int e = 0; e < 4; ++e) {
                c0[e] = bf16r(f0[e]); c0[4 + e] = bf16r(f1[e]);
                c1[e] = bf16r(f2[e]); c1[4 + e] = bf16r(f3[e]);
                c2[e] = bf16r(f5[e]); c2[4 + e] = 0;
                c3[e] = 0; c3[4 + e] = 0;
            }
            *(short8*)&sW[r * 40 + 0]  = c0;
            *(short8*)&sW[r * 40 + 8]  = c1;
            *(short8*)&sW[r * 40 + 16] = c2;
            *(short8*)&sW[r * 40 + 24] = c3;
        }
    }
    __syncthreads();

    if (w == 0) {
        f4 a3[3] = {};
#pragma unroll
        for (int kk = 0; kk < 13; ++kk) {
            short8 a = *(const short8*)&sA[(lr * 52 + ((kk * 4 + lg) ^ (lr & 3))) * 8];
#pragma unroll
            for (int ni = 0; ni < 3; ++ni) {
                int br = ni * 16 + lr;
                short8 b = *(const short8*)&sB[(br * 52 + ((kk * 4 + lg) ^ (br & 3))) * 8];
                a3[ni] = __builtin_amdgcn_mfma_f32_16x16x32_bf16(a, b, a3[ni], 0, 0, 0);
            }
        }
#pragma unroll
        for (int ni = 0; ni < 3; ++ni) {
            int n = ni * 16 + lr;
            if (n < 40) {
                float bias = (n < 20) ? b21[n] : b22[n - 20];
#pragma unroll
                for (int r = 0; r < 4; ++r) {
                    int row = lg * 4 + r;
                    float v = a3[ni][r] + bias;
                    if (n < 20) {
                        muv[0][row][n] = v;
                        out[OFF_MU + (size_t)(r0 + row) * 20 + n] = v;
                    } else {
                        muv[1][row][n - 20] = v;
                        out[OFF_LV + (size_t)(r0 + row) * 20 + (n - 20)] = v;
                    }
                }
            }
        }
    }
    __syncthreads();

    if (tid < 80) {
        int row = tid / 5, c = tid - (tid / 5) * 5;
        short8 v;
#pragma unroll
        for (int e = 0; e < 8; ++e) {
            int j = c * 8 + e;
            float val = 0.f;
            if (j < 20) {
                val = muv[0][row][j];
                if (j == 19) val -= SQRT20F * muv[1][row][19];
            }
            v[e] = bf16r(val);
        }
        *(short8*)&zl[row * 40 + c * 8] = v;
    } else if (tid < 176) {
        int t = tid - 80;
        int row = t / 6, c = t - (t / 6) * 6;
        short8 zz;
#pragma unroll
        for (int e = 0; e < 8; ++e) zz[e] = 0;
        *(short8*)&h3s[row * 448 + 400 + c * 8] = zz;
    }
#pragma unroll
    for (int it = 0; it < 13; ++it) {
        int p = it * 256 + tid;
        if (p < 3200) {
            int s = p / 80, q = p - s * 80;
            int row = q / 5, j4 = q - (q / 5) * 5;
            f4 v = *(const f4*)&muv[0][row][j4 * 4];
            int sp = (s < 20) ? s : s - 20;
            if ((sp >> 2) == j4) {
                float add = ((s < 20) ? SQRT20F : -SQRT20F) * muv[1][row][sp];
                int e = sp & 3;
#pragma unroll
                for (int k = 0; k < 4; ++k) v[k] += (e == k) ? add : 0.f;
            }
            *(f4*)(out + OFF_Z + ((size_t)s * BS + r0 + row) * 20 + j4 * 4) = v;
        }
    }
    __syncthreads();

    for (int f = w; f < 25; f += 4) {
        int n0 = f * 16;
        short8 a = *(const short8*)&zl[lr * 40 + lg * 8];
        short8 b = *(const short8*)&sW[(n0 + lr) * 40 + lg * 8];
        f4 z4 = {};
        f4 accv = __builtin_amdgcn_mfma_f32_16x16x32_bf16(a, b, z4, 0, 0, 0);
        int n = n0 + lr;
        float bias = b3[n];
#pragma unroll
        for (int r = 0; r < 4; ++r) {
            int row = lg * 4 + r;
            float v = accv[r] + bias;
            h3s[row * 448 + n] = bf16r(v > 0.f ? v : 0.f);
        }
    }
    __syncthreads();

#pragma unroll
    for (int it = 0; it < 4; ++it) {
        int p = it * 256 + tid;
        if (p < 896) {
            int row = p / 56, c = p - (p / 56) * 56;
            *(short8*)(h3b + (size_t)(r0 + row) * KPD + c * 8) =
                *(const short8*)&h3s[row * 448 + c * 8];
        }
    }
}

// ---------------------------------------------------------------------------
// K3: [recon_mu | recon_var] = h3b @ Wcat^T + bias
// M=4096, N=1568, K=448. BM=128, BN=112, BK=64, dbuf glds. grid 448.
// per-wave 32x112 -> 28 MFMA : 18 ds_read per K-step.
// ---------------------------------------------------------------------------
__global__ __launch_bounds__(256)
void k_gemm4(const short* __restrict__ h3b, const short* __restrict__ wcat,
             const float* __restrict__ b41, const float* __restrict__ b42,
             float* __restrict__ out) {
    __shared__ short sA[2][128 * 64];   // 16KB each
    __shared__ short sB[2][112 * 64];   // 14KB each

    const int tid = threadIdx.x;
    const int bid = blockIdx.x;
    const int swz = (bid & 7) * 56 + (bid >> 3);   // XCD-chunked
    const int bm = swz / 14, bn = swz - bm * 14;
    const int w = tid >> 6, l = tid & 63, lg = l >> 4, lr = l & 15;

    f4 acc[2][7] = {};

    auto stage = [&](int buf, int kt) {
#pragma unroll
        for (int i = 0; i < 4; ++i) {              // A: 1024 chunks
            int c = tid + i * 256;
            int r = c >> 3, kc = (c & 7) ^ (r & 7);
            glds16(h3b + (size_t)(bm * 128 + r) * KPD + kt * 64 + kc * 8, &sA[buf][c * 8]);
        }
#pragma unroll
        for (int i = 0; i < 4; ++i) {              // B: 896 chunks
            int c = tid + i * 256;
            if (c < 896) {
                int r = c >> 3, kc = (c & 7) ^ (r & 7);
                glds16(wcat + (size_t)(bn * 112 + r) * KPD + kt * 64 + kc * 8, &sB[buf][c * 8]);
            }
        }
    };

    stage(0, 0);
    __syncthreads();
    for (int kt = 0; kt < 7; ++kt) {
        const int cur = kt & 1;
        if (kt < 6) stage(cur ^ 1, kt + 1);
        const int row0 = w * 32 + lr, row1 = w * 32 + 16 + lr;
#pragma unroll
        for (int kk = 0; kk < 2; ++kk) {
            short8 a0 = *(const short8*)&sA[cur][(row0 * 8 + ((kk * 4 + lg) ^ (row0 & 7))) * 8];
            short8 a1 = *(const short8*)&sA[cur][(row1 * 8 + ((kk * 4 + lg) ^ (row1 & 7))) * 8];
#pragma unroll
            for (int ni = 0; ni < 7; ++ni) {
                int br = ni * 16 + lr;
                short8 b = *(const short8*)&sB[cur][(br * 8 + ((kk * 4 + lg) ^ (br & 7))) * 8];
                acc[0][ni] = __builtin_amdgcn_mfma_f32_16x16x32_bf16(a0, b, acc[0][ni], 0, 0, 0);
                acc[1][ni] = __builtin_amdgcn_mfma_f32_16x16x32_bf16(a1, b, acc[1][ni], 0, 0, 0);
            }
        }
        __syncthreads();
    }

    const bool first = (bn < 7);
#pragma unroll
    for (int mi = 0; mi < 2; ++mi)
#pragma unroll
        for (int ni = 0; ni < 7; ++ni) {
            int colt = bn * 112 + ni * 16 + lr;
            int cc = first ? colt : colt - 784;
            float bias = first ? b41[cc] : b42[cc];
            size_t base = first ? (size_t)OFF_RMU : (size_t)OFF_RVAR;
#pragma unroll
            for (int r = 0; r < 4; ++r) {
                size_t row = (size_t)(bm * 128 + w * 32 + mi * 16 + lg * 4 + r);
                out[base + row * DIN + cc] = acc[mi][ni][r] + bias;
            }
        }
}

// ---------------------------------------------------------------------------
extern "C" void kernel_launch(void* const* d_in, const int* in_sizes, int n_in,
                              void* d_out, int out_size, void* d_ws, size_t ws_size,
                              hipStream_t stream) {
    const float* x   = (const float*)d_in[0];
    const float* W1  = (const float*)d_in[1];
    const float* b1  = (const float*)d_in[2];
    const float* W21 = (const float*)d_in[3];
    const float* b21 = (const float*)d_in[4];
    const float* W22 = (const float*)d_in[5];
    const float* b22 = (const float*)d_in[6];
    const float* W3  = (const float*)d_in[7];
    const float* b3  = (const float*)d_in[8];
    const float* W41 = (const float*)d_in[9];
    const float* b41 = (const float*)d_in[10];
    const float* W42 = (const float*)d_in[11];
    const float* b42 = (const float*)d_in[12];

    float* out = (float*)d_out;
    char*  ws  = (char*)d_ws;
    const short* wcat = (const short*)(ws + WS_WCAT);
    const short* w2c  = (const short*)(ws + WS_W2C);
    const short* W1b  = (const short*)(ws + WS_W1B);
    short* h1b = (short*)(ws + WS_H1B);
    short* h3b = (short*)(ws + WS_H3B);

    k0<<<516, 256, 0, stream>>>(W1, W41, W42, W21, W22, ws);
    k1<<<320, 256, 0, stream>>>(x, b1, W1b, h1b);
    k_mid<<<256, 256, 0, stream>>>(h1b, w2c, W3, b3, b21, b22, out, h3b);
    k_gemm4<<<448, 256, 0, stream>>>(h3b, wcat, b41, b42, out);
}

// Round 11
// 43.250 us; speedup vs baseline: 3.9148x; 1.0411x over previous
//
#include <hip/hip_runtime.h>
#include <hip/hip_bf16.h>

// Problem dims
#define BS   4096
#define DIN  784
#define DH   400
#define DZ   20

#define KP1  832    // W1b row length (784 -> 832 = 13*64)
#define KPH  416    // h1b / W2c row length (400 -> 416)
#define KPD  448    // h3b / Wcat row length (400 -> 448)

// Output layout (f32 elements)
#define OFF_RMU  0
#define OFF_RVAR 3211264
#define OFF_MU   6422528
#define OFF_LV   6504448
#define OFF_Z    6586368

// Workspace layout (bytes)
#define WS_WCAT  0          // bf16 [1568][448] = 1404928 (rows 0..783 W41, 784.. W42)
#define WS_W2C   1404928    // bf16 [48][416]   = 39936
#define WS_W1B   1444864    // bf16 [400][832]  = 665600
#define WS_H1B   2110464    // bf16 [4096][416] = 3407872
#define WS_H3B   5518336    // bf16 [4096][448] = 3670016
// total 9188352 bytes

#define SQRT20F 4.47213595499958f

using short8 = __attribute__((ext_vector_type(8))) short;
using f4     = __attribute__((ext_vector_type(4))) float;
using i4     = __attribute__((ext_vector_type(4))) int;

__device__ __forceinline__ short bf16r(float f) {
    union { float f; unsigned u; } v; v.f = f;
    unsigned r = (v.u + 0x7fffu + ((v.u >> 16) & 1u)) >> 16;
    return (short)r;
}

// pack 8 f32 (raw bits q0=elems0..3, q1=elems4..7) -> 8 bf16 (truncated)
__device__ __forceinline__ i4 pack8(const i4 q0, const i4 q1) {
    i4 d;
    d[0] = (q0[1] & 0xffff0000) | (int)(((unsigned)q0[0]) >> 16);
    d[1] = (q0[3] & 0xffff0000) | (int)(((unsigned)q0[2]) >> 16);
    d[2] = (q1[1] & 0xffff0000) | (int)(((unsigned)q1[0]) >> 16);
    d[3] = (q1[3] & 0xffff0000) | (int)(((unsigned)q1[2]) >> 16);
    return d;
}

__device__ __forceinline__ void glds16(const void* g, void* l) {
    __builtin_amdgcn_global_load_lds(
        (const __attribute__((address_space(1))) unsigned int*)g,
        (__attribute__((address_space(3))) unsigned int*)l,
        16, 0, 0);
}

// ---------------------------------------------------------------------------
// k0: one-time weight conversion f32 -> bf16 (RTNE), zero K-padding.
// W1 -> W1b[400][832]; W41/W42 -> Wcat[1568][448]; W21/W22 -> W2c[48][416].
// ---------------------------------------------------------------------------
__global__ void k0(const float* __restrict__ W1, const float* __restrict__ W41,
                   const float* __restrict__ W42, const float* __restrict__ W21,
                   const float* __restrict__ W22, char* __restrict__ ws) {
    const int N0 = 400 * 104;                 // W1b
    const int N1 = N0 + 1568 * 56;            // Wcat
    const int N2 = N1 + 48 * 52;              // W2c
    int gid = blockIdx.x * 256 + threadIdx.x;
    if (gid >= N2) return;

    const float* sr = nullptr;
    short* dst;
    int c, DC;
    if (gid < N0) {
        int row = gid / 104; c = gid - row * 104; DC = 98;
        sr = W1 + (size_t)row * DIN;
        dst = (short*)(ws + WS_W1B) + (size_t)row * KP1 + c * 8;
    } else if (gid < N1) {
        int p = gid - N0;
        int row = p / 56; c = p - row * 56; DC = 50;
        sr = (row < 784) ? (W41 + (size_t)row * DH) : (W42 + (size_t)(row - 784) * DH);
        dst = (short*)(ws + WS_WCAT) + (size_t)row * KPD + c * 8;
    } else {
        int p = gid - N1;
        int row = p / 52; c = p - row * 52; DC = 50;
        if (row < 20)      sr = W21 + (size_t)row * DH;
        else if (row < 40) sr = W22 + (size_t)(row - 20) * DH;
        else               sr = nullptr;
        dst = (short*)(ws + WS_W2C) + (size_t)row * KPH + c * 8;
    }
    short8 v;
    if (c < DC && sr) {
        f4 a = *(const f4*)(sr + c * 8);
        f4 b = *(const f4*)(sr + c * 8 + 4);
#pragma unroll
        for (int e = 0; e < 4; ++e) { v[e] = bf16r(a[e]); v[4 + e] = bf16r(b[e]); }
    } else {
#pragma unroll
        for (int e = 0; e < 8; ++e) v[e] = 0;
    }
    *(short8*)dst = v;
}

// ---------------------------------------------------------------------------
// k1: h1b = bf16(relu(x @ W1^T + b1)). BM=64, BN=80, BK=64, 13 steps, dbuf.
// A (x f32) reg-staged with bit-truncation; B (W1b) via global_load_lds.
// grid 320 (XCD-swizzled), 256 threads.  [r4-exact]
// ---------------------------------------------------------------------------
__global__ __launch_bounds__(256)
void k1(const float* __restrict__ x, const float* __restrict__ b1,
        const short* __restrict__ W1b, short* __restrict__ h1b) {
    __shared__ short sA[2][64 * 64];   // 8KB each
    __shared__ short sB[2][80 * 64];   // 10KB each

    const int tid = threadIdx.x;
    const int bid = blockIdx.x;
    const int swz = (bid & 7) * 40 + (bid >> 3);
    const int bm = swz / 5, bn = swz - bm * 5;
    const int w = tid >> 6, l = tid & 63, lg = l >> 4, lr = l & 15;

    f4 acc[5] = {};
    i4 ar[4];

    auto a_load = [&](int kt) {
#pragma unroll
        for (int i = 0; i < 2; ++i) {
            int c = tid + i * 256;
            int row = c >> 3, kc = c & 7;
            int gk = kt * 64 + kc * 8;
            if (gk < DIN) {
                const i4* p = (const i4*)(x + (size_t)(bm * 64 + row) * DIN + gk);
                ar[2 * i] = p[0]; ar[2 * i + 1] = p[1];
            } else {
                ar[2 * i] = (i4){0, 0, 0, 0};
                ar[2 * i + 1] = (i4){0, 0, 0, 0};
            }
        }
    };
    auto a_write = [&](int buf) {
#pragma unroll
        for (int i = 0; i < 2; ++i) {
            int c = tid + i * 256;
            int row = c >> 3, kc = c & 7;
            *(i4*)&sA[buf][(row * 8 + (kc ^ (row & 7))) * 8] = pack8(ar[2 * i], ar[2 * i + 1]);
        }
    };
    auto b_stage = [&](int buf, int kt) {
#pragma unroll
        for (int it = 0; it < 3; ++it) {
            int p = it * 256 + tid;
            if (p < 640) {
                int r = p >> 3, kc = (p & 7) ^ (r & 7);
                glds16(W1b + (size_t)(bn * 80 + r) * KP1 + kt * 64 + kc * 8, &sB[buf][p * 8]);
            }
        }
    };
    auto compute = [&](int buf) {
        const int row = w * 16 + lr;
#pragma unroll
        for (int kk = 0; kk < 2; ++kk) {
            short8 a = *(const short8*)&sA[buf][(row * 8 + ((kk * 4 + lg) ^ (row & 7))) * 8];
#pragma unroll
            for (int ni = 0; ni < 5; ++ni) {
                int brw = ni * 16 + lr;
                short8 b = *(const short8*)&sB[buf][(brw * 8 + ((kk * 4 + lg) ^ (brw & 7))) * 8];
                acc[ni] = __builtin_amdgcn_mfma_f32_16x16x32_bf16(a, b, acc[ni], 0, 0, 0);
            }
        }
    };

    a_load(0); b_stage(0, 0); a_write(0);
    __syncthreads();
    for (int kt = 0; kt < 13; ++kt) {
        const int cur = kt & 1;
        if (kt < 12) { a_load(kt + 1); b_stage(cur ^ 1, kt + 1); }
        compute(cur);
        if (kt < 12) a_write(cur ^ 1);
        __syncthreads();
    }

#pragma unroll
    for (int ni = 0; ni < 5; ++ni) {
        int col = bn * 80 + ni * 16 + lr;
        float bias = b1[col];
#pragma unroll
        for (int r = 0; r < 4; ++r) {
            int row = bm * 64 + w * 16 + lg * 4 + r;
            float v = acc[ni][r] + bias;
            h1b[(size_t)row * KPH + col] = bf16r(v > 0.f ? v : 0.f);
        }
    }
    if (bn == 4) {
        for (int p = tid; p < 64 * 16; p += 256) {
            int r = p >> 4, c = 400 + (p & 15);
            h1b[(size_t)(bm * 64 + r) * KPH + c] = 0;
        }
    }
}

// ---------------------------------------------------------------------------
// K2 (mid): 512 threads, per block 16 batch rows: mu/lv MFMA -> out+LDS;
// z writes; h3 MFMA -> h3b (coalesced via LDS). grid 256.
// ---------------------------------------------------------------------------
__global__ __launch_bounds__(512, 1)
void k_mid(const short* __restrict__ h1b, const short* __restrict__ w2c,
           const float* __restrict__ W3, const float* __restrict__ b3,
           const float* __restrict__ b21, const float* __restrict__ b22,
           float* __restrict__ out, short* __restrict__ h3b) {
    __shared__ short sA[16 * 416];
    __shared__ short sB[48 * 416];
    __shared__ short sW[400 * 40];
    __shared__ float muv[2][16][20];
    __shared__ short zl[16 * 40];
    __shared__ short h3s[16 * 448];

    const int tid = threadIdx.x;
    const int blk = blockIdx.x;
    const int w = tid >> 6, l = tid & 63, lg = l >> 4, lr = l & 15;
    const int r0 = blk * 16;

#pragma unroll
    for (int it = 0; it < 2; ++it) {            // sA: 832 chunks
        int p = it * 512 + tid;
        if (p < 832) {
            int r = p / 52, cp = p - r * 52, c = cp ^ (r & 3);
            glds16(h1b + (size_t)(r0 + r) * KPH + c * 8, &sA[p * 8]);
        }
    }
#pragma unroll
    for (int it = 0; it < 5; ++it) {            // sB: 2496 chunks
        int p = it * 512 + tid;
        if (p < 2496) {
            int r = p / 52, cp = p - r * 52, c = cp ^ (r & 3);
            glds16(w2c + (size_t)r * KPH + c * 8, &sB[p * 8]);
        }
    }
    if (tid < 400) {                            // sW: W3 -> bf16 [400][40]
        int r = tid;
        const float* src = W3 + (size_t)r * DZ;
        f4 f0 = *(const f4*)src;
        f4 f1 = *(const f4*)(src + 4);
        f4 f2 = *(const f4*)(src + 8);
        f4 f3 = *(const f4*)(src + 12);
        f4 f5 = *(const f4*)(src + 16);
        short8 c0, c1, c2, c3;
#pragma unroll
        for (int e = 0; e < 4; ++e) {
            c0[e] = bf16r(f0[e]); c0[4 + e] = bf16r(f1[e]);
            c1[e] = bf16r(f2[e]); c1[4 + e] = bf16r(f3[e]);
            c2[e] = bf16r(f5[e]); c2[4 + e] = 0;
            c3[e] = 0; c3[4 + e] = 0;
        }
        *(short8*)&sW[r * 40 + 0]  = c0;
        *(short8*)&sW[r * 40 + 8]  = c1;
        *(short8*)&sW[r * 40 + 16] = c2;
        *(short8*)&sW[r * 40 + 24] = c3;
    }
    __syncthreads();

    if (w == 0) {                               // mu/lv MFMA (wave 0)
        f4 a3[3] = {};
#pragma unroll
        for (int kk = 0; kk < 13; ++kk) {
            short8 a = *(const short8*)&sA[(lr * 52 + ((kk * 4 + lg) ^ (lr & 3))) * 8];
#pragma unroll
            for (int ni = 0; ni < 3; ++ni) {
                int br = ni * 16 + lr;
                short8 b = *(const short8*)&sB[(br * 52 + ((kk * 4 + lg) ^ (br & 3))) * 8];
                a3[ni] = __builtin_amdgcn_mfma_f32_16x16x32_bf16(a, b, a3[ni], 0, 0, 0);
            }
        }
#pragma unroll
        for (int ni = 0; ni < 3; ++ni) {
            int n = ni * 16 + lr;
            if (n < 40) {
                float bias = (n < 20) ? b21[n] : b22[n - 20];
#pragma unroll
                for (int r = 0; r < 4; ++r) {
                    int row = lg * 4 + r;
                    float v = a3[ni][r] + bias;
                    if (n < 20) {
                        muv[0][row][n] = v;
                        out[OFF_MU + (size_t)(r0 + row) * 20 + n] = v;
                    } else {
                        muv[1][row][n - 20] = v;
                        out[OFF_LV + (size_t)(r0 + row) * 20 + (n - 20)] = v;
                    }
                }
            }
        }
    }
    __syncthreads();

    if (tid < 80) {                             // z_last bf16 [16][40]
        int row = tid / 5, c = tid - (tid / 5) * 5;
        short8 v;
#pragma unroll
        for (int e = 0; e < 8; ++e) {
            int j = c * 8 + e;
            float val = 0.f;
            if (j < 20) {
                val = muv[0][row][j];
                if (j == 19) val -= SQRT20F * muv[1][row][19];
            }
            v[e] = bf16r(val);
        }
        *(short8*)&zl[row * 40 + c * 8] = v;
    } else if (tid < 176) {                     // h3s pad cols 400..447
        int t = tid - 80;
        int row = t / 6, c = t - (t / 6) * 6;
        short8 zz;
#pragma unroll
        for (int e = 0; e < 8; ++e) zz[e] = 0;
        *(short8*)&h3s[row * 448 + 400 + c * 8] = zz;
    }
#pragma unroll
    for (int it = 0; it < 7; ++it) {            // z: 3200 f4-chunks
        int p = it * 512 + tid;
        if (p < 3200) {
            int s = p / 80, q = p - s * 80;
            int row = q / 5, j4 = q - (q / 5) * 5;
            f4 v = *(const f4*)&muv[0][row][j4 * 4];
            int sp = (s < 20) ? s : s - 20;
            if ((sp >> 2) == j4) {
                float add = ((s < 20) ? SQRT20F : -SQRT20F) * muv[1][row][sp];
                int e = sp & 3;
#pragma unroll
                for (int k = 0; k < 4; ++k) v[k] += (e == k) ? add : 0.f;
            }
            *(f4*)(out + OFF_Z + ((size_t)s * BS + r0 + row) * 20 + j4 * 4) = v;
        }
    }
    __syncthreads();

    for (int f = w; f < 25; f += 8) {           // h3 MFMA, 8 waves
        int n0 = f * 16;
        short8 a = *(const short8*)&zl[lr * 40 + lg * 8];
        short8 b = *(const short8*)&sW[(n0 + lr) * 40 + lg * 8];
        f4 z4 = {};
        f4 accv = __builtin_amdgcn_mfma_f32_16x16x32_bf16(a, b, z4, 0, 0, 0);
        int n = n0 + lr;
        float bias = b3[n];
#pragma unroll
        for (int r = 0; r < 4; ++r) {
            int row = lg * 4 + r;
            float v = accv[r] + bias;
            h3s[row * 448 + n] = bf16r(v > 0.f ? v : 0.f);
        }
    }
    __syncthreads();

#pragma unroll
    for (int it = 0; it < 2; ++it) {            // coalesced h3b dump
        int p = it * 512 + tid;
        if (p < 896) {
            int row = p / 56, c = p - (p / 56) * 56;
            *(short8*)(h3b + (size_t)(r0 + row) * KPD + c * 8) =
                *(const short8*)&h3s[row * 448 + c * 8];
        }
    }
}

// ---------------------------------------------------------------------------
// K3: [recon_mu | recon_var] = h3b @ Wcat^T + bias
// M=4096, N=1568, K=448. BM=128, BN=112, BK=64, dbuf glds. grid 448,
// 512 threads (8 waves; per-wave 16x112 -> 14 MFMA : 16 ds_read per step).
// ---------------------------------------------------------------------------
__global__ __launch_bounds__(512)
void k_gemm4(const short* __restrict__ h3b, const short* __restrict__ wcat,
             const float* __restrict__ b41, const float* __restrict__ b42,
             float* __restrict__ out) {
    __shared__ short sA[2][128 * 64];   // 16KB each
    __shared__ short sB[2][112 * 64];   // 14KB each

    const int tid = threadIdx.x;
    const int bid = blockIdx.x;
    const int swz = (bid & 7) * 56 + (bid >> 3);   // XCD-chunked (448%8==0)
    const int bm = swz / 14, bn = swz - bm * 14;
    const int w = tid >> 6, l = tid & 63, lg = l >> 4, lr = l & 15;

    f4 acc[7] = {};

    auto stage = [&](int buf, int kt) {
#pragma unroll
        for (int i = 0; i < 2; ++i) {              // A: 1024 chunks
            int c = tid + i * 512;
            int r = c >> 3, kc = (c & 7) ^ (r & 7);
            glds16(h3b + (size_t)(bm * 128 + r) * KPD + kt * 64 + kc * 8, &sA[buf][c * 8]);
        }
#pragma unroll
        for (int i = 0; i < 2; ++i) {              // B: 896 chunks
            int c = tid + i * 512;
            if (c < 896) {
                int r = c >> 3, kc = (c & 7) ^ (r & 7);
                glds16(wcat + (size_t)(bn * 112 + r) * KPD + kt * 64 + kc * 8, &sB[buf][c * 8]);
            }
        }
    };

    stage(0, 0);
    __syncthreads();
    for (int kt = 0; kt < 7; ++kt) {
        const int cur = kt & 1;
        if (kt < 6) stage(cur ^ 1, kt + 1);
        const int row = w * 16 + lr;               // 8 waves x 16 rows = 128
#pragma unroll
        for (int kk = 0; kk < 2; ++kk) {
            short8 a = *(const short8*)&sA[cur][(row * 8 + ((kk * 4 + lg) ^ (row & 7))) * 8];
#pragma unroll
            for (int ni = 0; ni < 7; ++ni) {
                int br = ni * 16 + lr;
                short8 b = *(const short8*)&sB[cur][(br * 8 + ((kk * 4 + lg) ^ (br & 7))) * 8];
                acc[ni] = __builtin_amdgcn_mfma_f32_16x16x32_bf16(a, b, acc[ni], 0, 0, 0);
            }
        }
        __syncthreads();
    }

    const bool first = (bn < 7);
#pragma unroll
    for (int ni = 0; ni < 7; ++ni) {
        int colt = bn * 112 + ni * 16 + lr;
        int cc = first ? colt : colt - 784;
        float bias = first ? b41[cc] : b42[cc];
        size_t base = first ? (size_t)OFF_RMU : (size_t)OFF_RVAR;
#pragma unroll
        for (int r = 0; r < 4; ++r) {
            size_t row = (size_t)(bm * 128 + w * 16 + lg * 4 + r);
            out[base + row * DIN + cc] = acc[ni][r] + bias;
        }
    }
}

// ---------------------------------------------------------------------------
extern "C" void kernel_launch(void* const* d_in, const int* in_sizes, int n_in,
                              void* d_out, int out_size, void* d_ws, size_t ws_size,
                              hipStream_t stream) {
    const float* x   = (const float*)d_in[0];
    const float* W1  = (const float*)d_in[1];
    const float* b1  = (const float*)d_in[2];
    const float* W21 = (const float*)d_in[3];
    const float* b21 = (const float*)d_in[4];
    const float* W22 = (const float*)d_in[5];
    const float* b22 = (const float*)d_in[6];
    const float* W3  = (const float*)d_in[7];
    const float* b3  = (const float*)d_in[8];
    const float* W41 = (const float*)d_in[9];
    const float* b41 = (const float*)d_in[10];
    const float* W42 = (const float*)d_in[11];
    const float* b42 = (const float*)d_in[12];

    float* out = (float*)d_out;
    char*  ws  = (char*)d_ws;
    const short* wcat = (const short*)(ws + WS_WCAT);
    const short* w2c  = (const short*)(ws + WS_W2C);
    const short* W1b  = (const short*)(ws + WS_W1B);
    short* h1b = (short*)(ws + WS_H1B);
    short* h3b = (short*)(ws + WS_H3B);

    k0<<<516, 256, 0, stream>>>(W1, W41, W42, W21, W22, ws);
    k1<<<320, 256, 0, stream>>>(x, b1, W1b, h1b);
    k_mid<<<256, 512, 0, stream>>>(h1b, w2c, W3, b3, b21, b22, out, h3b);
    k_gemm4<<<448, 512, 0, stream>>>(h3b, wcat, b41, b42, out);
}